// Round 7
// baseline (872.593 us; speedup 1.0000x reference)
//
#include <hip/hip_runtime.h>

#define NB 2048
#define HDM 64
#define NLAY 5

typedef __bf16 bf16x8 __attribute__((ext_vector_type(8)));
typedef float v4f __attribute__((ext_vector_type(4)));

__device__ __forceinline__ float sigmoidf_(float x){ return 1.f/(1.f+__expf(-x)); }
__device__ __forceinline__ float tanhfast_(float x){
  x = fminf(fmaxf(x, -15.f), 15.f);
  float e = __expf(2.f*x);
  return (e-1.f)/(e+1.f);
}
__device__ __forceinline__ unsigned short f2b_rne(float f){
  unsigned u = __float_as_uint(f);
  unsigned r = u + 0x7FFFu + ((u>>16)&1u);
  return (unsigned short)(r>>16);
}
__device__ __forceinline__ unsigned pk2(float a, float b){
  unsigned ua = (__float_as_uint(a) + 0x8000u) >> 16;
  unsigned ub = (__float_as_uint(b) + 0x8000u) & 0xFFFF0000u;
  return ua | ub;
}

struct MP {
  const float *x, *tt, *freqs, *fc1W, *fc1b, *fc2W, *fc2b, *tprojW, *tprojb;
  const float *nodeW, *nodeb, *tcatW, *tcatb, *penb, *pelW, *pelb, *catW, *catb;
  const float *convWg, *gruWih, *grubih, *gruWhh, *grubhh;
  const float *Wqkv, *bqkv, *Wo, *bo, *bng, *bnb, *W1, *b1, *W2, *b2, *outW, *outb;
  float *out;
  unsigned *cnt;           // grid-barrier counter (zeroed by memsetAsync)
  float *hsum;             // 64 (layer-0 only; zeroed)
  float *bnacc;            // 5*384 (zeroed)
  unsigned short *Kb, *Vt; // bf16 K (padded dh32) and V^T
  float *h0p;              // 2 x 2048 x 64 GEMM1 partials
  float *smlpG;            // 2048 x 64 (layer-4 smlp for the output GEMM)
};

// Grid barrier, cache-friendly version:
//  - arrival: RELEASE fetch_add (one L2 writeback publishes this block's stores)
//  - spin: RELAXED atomic load (LLC-coherent, NO per-iteration cache invalidate)
//  - exit: one ACQUIRE fence per block (single invalidate), after __syncthreads
__device__ __forceinline__ void gbar(unsigned* cnt, unsigned& ph){
  __syncthreads();
  if (threadIdx.x == 0){
    ph += 1;
    unsigned tgt = ph * 256u;
    __hip_atomic_fetch_add(cnt, 1u, __ATOMIC_RELEASE, __HIP_MEMORY_SCOPE_AGENT);
    while (__hip_atomic_load(cnt, __ATOMIC_RELAXED, __HIP_MEMORY_SCOPE_AGENT) < tgt)
      __builtin_amdgcn_s_sleep(8);
  }
  __syncthreads();
  __builtin_amdgcn_fence(__ATOMIC_ACQUIRE, "agent");
}

__global__ __launch_bounds__(512) void k_mega(MP p)
{
  __shared__ float LDSf[11264];          // 44 KB
  float* hL    = LDSf;                   // 512  (8x64, persists within layer)
  float* ghL   = LDSf + 512;             // 1536 (8x192)
  float* qL    = LDSf + 2048;            // 512  (8x64 fp32 Q)
  float* smlpL = LDSf + 2560;            // 512  (8x64, persists to next layer)
  float* TR    = LDSf + 3072;            // 8192 transient floats

  const int t = threadIdx.x, blk = blockIdx.x;
  const int row0 = blk*8;
  unsigned bph = 0;

  // ================= P0: GEMM1 partial (block = 16 rows x half-K) =================
  {
    const int rt = blk>>1, kq = blk&1;
    const int rows0 = rt*16, k0 = kq*2048;
    const int col4 = (t&15)*4, rq4 = ((t>>4)&3)*4, ks = t>>6;
    float4 a0={0,0,0,0}, a1={0,0,0,0}, a2={0,0,0,0}, a3={0,0,0,0};
    for (int ch=0; ch<8; ++ch){
      __syncthreads();
      #pragma unroll
      for (int i=0;i<2;++i){
        int fi = t + 512*i;
        int xr = fi>>6, kk = (fi&63)<<2;
        *(float4*)&TR[xr*260+kk] = *(const float4*)&p.x[(size_t)(rows0+xr)*4096 + k0 + ch*256 + kk];
      }
      __syncthreads();
      const float* wp = &p.nodeW[(size_t)(k0 + ch*256 + ks*32)*64 + col4];
      const float* xp = &TR[rq4*260 + ks*32];
      #pragma unroll 8
      for (int kk=0; kk<32; ++kk){
        float4 w = *(const float4*)&wp[kk*64];
        float x0 = xp[kk], x1 = xp[260+kk], x2 = xp[520+kk], x3 = xp[780+kk];
        a0.x += x0*w.x; a0.y += x0*w.y; a0.z += x0*w.z; a0.w += x0*w.w;
        a1.x += x1*w.x; a1.y += x1*w.y; a1.z += x1*w.z; a1.w += x1*w.w;
        a2.x += x2*w.x; a2.y += x2*w.y; a2.z += x2*w.z; a2.w += x2*w.w;
        a3.x += x3*w.x; a3.y += x3*w.y; a3.z += x3*w.z; a3.w += x3*w.w;
      }
    }
    __syncthreads();
    *(float4*)&TR[ks*1024 + (rq4+0)*64 + col4] = a0;
    *(float4*)&TR[ks*1024 + (rq4+1)*64 + col4] = a1;
    *(float4*)&TR[ks*1024 + (rq4+2)*64 + col4] = a2;
    *(float4*)&TR[ks*1024 + (rq4+3)*64 + col4] = a3;
    __syncthreads();
    if (t < 256){
      int row = t>>4, c4 = (t&15)*4;
      float4 s = {0,0,0,0};
      #pragma unroll
      for (int q=0;q<8;++q){
        float4 v = *(const float4*)&TR[q*1024 + row*64 + c4];
        s.x+=v.x; s.y+=v.y; s.z+=v.z; s.w+=v.w;
      }
      *(float4*)&p.h0p[(size_t)kq*(NB*64) + (size_t)(rows0+row)*64 + c4] = s;
    }
  }
  gbar(p.cnt, bph);

  // ================= layers =================
  for (int l=0; l<NLAY; ++l){
    // ---------- S1: hL (assemble or bn3-of-prev) + qkv/gh ----------
    if (l == 0){
      float* tb0 = TR;        float* tb1 = TR+512;
      float* htL = TR+1024;   float* h0L = TR+1536;
      float* hcat= TR+2048;   float* cvec= TR+2560;
      const int r = t>>6, c = t&63;
      const int row = row0 + r;
      float tv = p.tt[row];
      float te[16];
      #pragma unroll
      for (int j=0;j<8;++j){
        float sv, cv;
        __sincosf(6.28318530717958647692f*tv*p.freqs[j], &sv, &cv);
        te[j]=sv; te[j+8]=cv;
      }
      float a = p.fc1b[c];
      #pragma unroll
      for (int j=0;j<16;++j) a += te[j]*p.fc1W[j*64+c];
      tb0[r*64+c] = a*sigmoidf_(a);
      h0L[r*64+c] = p.nodeb[c] + p.h0p[(size_t)row*64+c] + p.h0p[(size_t)NB*64 + (size_t)row*64+c];
      if (t < 64){
        float pl[16];
        #pragma unroll
        for (int j=0;j<16;++j){
          float pa = p.pelb[j];
          for (int wv=0;wv<20;++wv) pa += p.penb[wv]*p.pelW[wv*16+j];
          pl[j]=pa;
        }
        float cv = p.catb[t];
        #pragma unroll
        for (int j=0;j<16;++j) cv += pl[j]*p.catW[(64+j)*64+t];
        cvec[t]=cv;
      }
      __syncthreads();
      float b2v = p.fc2b[c];
      #pragma unroll 8
      for (int k=0;k<64;++k) b2v += tb0[r*64+k]*p.fc2W[k*64+c];
      tb1[r*64+c] = b2v;
      __syncthreads();
      float ht = p.tprojb[c];
      #pragma unroll 8
      for (int k=0;k<64;++k) ht += tb1[r*64+k]*p.tprojW[k*64+c];
      htL[r*64+c] = ht;
      __syncthreads();
      float ac = p.tcatb[c];
      #pragma unroll 4
      for (int k=0;k<64;++k){
        ac += h0L[r*64+k]*p.tcatW[k*64+c];
        ac += htL[r*64+k]*p.tcatW[(64+k)*64+c];
      }
      hcat[r*64+c] = ac;
      __syncthreads();
      float hv = cvec[c];
      #pragma unroll 8
      for (int k=0;k<64;++k) hv += hcat[r*64+k]*p.catW[k*64+c];
      hL[r*64+c] = hv;
      __syncthreads();
      if (t < 64){
        float s = 0.f;
        #pragma unroll
        for (int rl=0;rl<8;++rl) s += hL[rl*64+t];
        atomicAdd(&p.hsum[t], s);
      }
    } else {
      const float* stp = p.bnacc + (l-1)*384;
      const float* gP = p.bng + (l-1)*192 + 128;
      const float* bP = p.bnb + (l-1)*192 + 128;
      const int c = t&63, rg = t>>6;
      float mu = stp[256+c]*(1.f/NB);
      float va = stp[320+c]*(1.f/NB) - mu*mu;
      hL[rg*64+c] = gP[c]*(smlpL[rg*64+c]-mu)*rsqrtf(va+1e-5f)+bP[c];
      __syncthreads();
    }
    // qkv + gh for own 8 rows (two 192-wide column groups, 4 rows each)
    {
      int grp = -1, cc = 0;
      if (t < 192){ grp = 0; cc = t; }
      else if (t >= 256 && t < 448){ grp = 1; cc = t-256; }
      if (grp >= 0){
        const float* Whh = p.gruWhh + l*12288;
        const float* Wq  = p.Wqkv  + l*12288;
        float ag[4], aq[4];
        float bh = p.grubhh[l*192+cc], bqv = p.bqkv[l*192+cc];
        #pragma unroll
        for (int rl=0;rl<4;++rl){ ag[rl]=bh; aq[rl]=bqv; }
        const int rb = grp*4;
        #pragma unroll 4
        for (int k=0;k<64;++k){
          float wh = Whh[k*192+cc];
          float wq = Wq [k*192+cc];
          #pragma unroll
          for (int rl=0;rl<4;++rl){
            float hk = hL[(rb+rl)*64+k];
            ag[rl] += hk*wh;
            aq[rl] += hk*wq;
          }
        }
        #pragma unroll
        for (int rl=0;rl<4;++rl){
          int r4 = rb+rl, rw = row0 + r4;
          ghL[r4*192+cc] = ag[rl];
          float av = aq[rl];
          if (cc < 64){
            qL[r4*64+cc] = av;
          } else if (cc < 128){
            int c2 = cc-64, hd = c2>>4, dh = c2&15;
            size_t base = ((size_t)(hd<<11) + rw)*32;
            p.Kb[base+dh] = f2b_rne(av);
            p.Kb[base+16+dh] = 0;
          } else {
            int c2 = cc-128, hd = c2>>4, dh = c2&15;
            p.Vt[((size_t)(hd*16+dh))*2048 + rw] = f2b_rne(av);
          }
        }
      }
    }
    gbar(p.cnt, bph);

    // ---------- S2: attention (own 8 rows, padded q16) + o-proj + GRU + bn1/2 stats ----------
    {
      float* smv = TR;     float* gi = TR+64;
      if (t < 64){
        const float* Wg = p.convWg + l*4096;
        float a = 0.f;
        if (l == 0){
          #pragma unroll 8
          for (int k=0;k<64;++k) a += p.hsum[k]*Wg[k*64+t];
        } else {
          const float* bP = p.bnb + (l-1)*192 + 128;
          #pragma unroll 8
          for (int k=0;k<64;++k) a += (2048.f*bP[k])*Wg[k*64+t];
        }
        smv[t]=a;
      }
      __syncthreads();
      if (t < 192){
        const float* Wih = p.gruWih + l*12288;
        float a = p.grubih[l*192+t];
        #pragma unroll 8
        for (int k=0;k<64;++k) a += smv[k]*Wih[k*192+t];
        gi[t]=a;
      }
      // --- attention: wave w = (head w>>1, key-half w&1), 1024 keys, 32 iters ---
      {
        const int w = t>>6, lane = t&63;
        const int q15 = lane&15, quad = lane>>4;
        const int head = w>>1, e = w&1;
        const int key00 = e*1024;
        unsigned short* Plw = (unsigned short*)(TR+256) + w*640;
        bf16x8 qf;
        {
          unsigned short* qp = (unsigned short*)&qf;
          #pragma unroll
          for (int j=0;j<8;++j){
            int dh = quad*8+j;
            float v = (q15 < 8 && dh < 16) ? qL[q15*64 + head*16 + dh]*0.25f : 0.f;
            qp[j] = f2b_rne(v);
          }
        }
        const unsigned short* Kb_h = p.Kb + ((size_t)(head<<11))*32;
        const unsigned short* Vrow = p.Vt + ((size_t)(head*16+q15))*2048;
        v4f O = {0.f,0.f,0.f,0.f};
        float m = -1e30f, lsum = 0.f;
        bf16x8 kf0 = *(const bf16x8*)&Kb_h[(size_t)(key00 + q15)*32 + quad*8];
        bf16x8 kf1 = *(const bf16x8*)&Kb_h[(size_t)(key00 + 16 + q15)*32 + quad*8];
        bf16x8 vf  = *(const bf16x8*)&Vrow[key00 + quad*8];
        for (int c=0; c<32; ++c){
          bf16x8 nk0, nk1, nv;
          if (c < 31){
            int nk = key00 + (c+1)*32;
            nk0 = *(const bf16x8*)&Kb_h[(size_t)(nk + q15)*32 + quad*8];
            nk1 = *(const bf16x8*)&Kb_h[(size_t)(nk + 16 + q15)*32 + quad*8];
            nv  = *(const bf16x8*)&Vrow[nk + quad*8];
          }
          v4f z = {0.f,0.f,0.f,0.f};
          v4f s0 = __builtin_amdgcn_mfma_f32_16x16x32_bf16(kf0, qf, z, 0,0,0);
          v4f s1 = __builtin_amdgcn_mfma_f32_16x16x32_bf16(kf1, qf, z, 0,0,0);
          float cmax = fmaxf(fmaxf(fmaxf(s0[0],s0[1]),fmaxf(s0[2],s0[3])),
                             fmaxf(fmaxf(s1[0],s1[1]),fmaxf(s1[2],s1[3])));
          cmax = fmaxf(cmax, __shfl_xor(cmax,16,64));
          cmax = fmaxf(cmax, __shfl_xor(cmax,32,64));
          float mnew = fmaxf(m, cmax);
          float alpha = __expf(m - mnew);
          float p0=__expf(s0[0]-mnew), p1=__expf(s0[1]-mnew), p2=__expf(s0[2]-mnew), p3=__expf(s0[3]-mnew);
          float p4=__expf(s1[0]-mnew), p5=__expf(s1[1]-mnew), p6=__expf(s1[2]-mnew), p7=__expf(s1[3]-mnew);
          lsum = alpha*lsum + ((p0+p1)+(p2+p3)+((p4+p5)+(p6+p7)));
          m = mnew;
          O[0]*=alpha; O[1]*=alpha; O[2]*=alpha; O[3]*=alpha;
          *(uint2*)&Plw[q15*40 + quad*4]      = make_uint2(pk2(p0,p1), pk2(p2,p3));
          *(uint2*)&Plw[q15*40 + 16 + quad*4] = make_uint2(pk2(p4,p5), pk2(p6,p7));
          asm volatile("s_waitcnt lgkmcnt(0)" ::: "memory");
          bf16x8 pf = *(const bf16x8*)&Plw[q15*40 + quad*8];
          O = __builtin_amdgcn_mfma_f32_16x16x32_bf16(vf, pf, O, 0,0,0);
          kf0 = nk0; kf1 = nk1; vf = nv;
        }
        lsum += __shfl_xor(lsum,16,64);
        lsum += __shfl_xor(lsum,32,64);
        float* Os = TR+2816; float* ms = TR+4992; float* ls = TR+5120;
        #pragma unroll
        for (int j=0;j<4;++j) Os[w*272 + q15*17 + quad*4 + j] = O[j];
        if (quad==0){ ms[w*16+q15]=m; ls[w*16+q15]=lsum; }
      }
      __syncthreads();
      // merge two key-halves per head -> oL[8][64]
      {
        float* Os = TR+2816; float* ms = TR+4992; float* ls = TR+5120; float* oL = TR+5248;
        const int q = t>>6, c = t&63;
        const int head = c>>4, dh = c&15;
        const int w0 = head*2, w1 = w0+1;
        float m0 = ms[w0*16+q], m1 = ms[w1*16+q];
        float mm = fmaxf(m0,m1);
        float a0 = __expf(m0-mm), a1 = __expf(m1-mm);
        float ll = a0*ls[w0*16+q] + a1*ls[w1*16+q];
        float oo = a0*Os[w0*272+q*17+dh] + a1*Os[w1*272+q*17+dh];
        oL[q*64+c] = oo / ll;
      }
      __syncthreads();
      // o-proj + GRU
      {
        float* oL = TR+5248; float* Sb1 = TR+5760; float* Sb2 = TR+6272;
        const int c = t&63, rg = t>>6;
        const float* Wo = p.Wo + l*4096;
        float o2 = p.bo[l*64+c];
        #pragma unroll 8
        for (int k=0;k<64;++k) o2 += oL[rg*64+k]*Wo[k*64+c];
        float hv = hL[rg*64+c];
        float s2v = o2 + hv;
        float ir  = gi[c]      + ghL[rg*192+c];
        float iz  = gi[64+c]   + ghL[rg*192+64+c];
        float inn = gi[128+c];
        float hn  = ghL[rg*192+128+c];
        float rr_ = sigmoidf_(ir);
        float zz  = sigmoidf_(iz);
        float nn  = tanhfast_(inn + rr_*hn);
        float s1v = (1.f-zz)*nn + zz*hv + hv;   // hc + h
        Sb1[rg*64+c] = s1v;
        Sb2[rg*64+c] = s2v;
      }
      __syncthreads();
      if (t < 64){
        float* Sb1 = TR+5760; float* Sb2 = TR+6272;
        float* st = p.bnacc + l*384;
        float a=0.f,aq=0.f,b=0.f,bq2=0.f;
        #pragma unroll
        for (int rl=0;rl<8;++rl){
          float v1 = Sb1[rl*64+t], v2 = Sb2[rl*64+t];
          a+=v1; aq+=v1*v1; b+=v2; bq2+=v2*v2;
        }
        atomicAdd(&st[t],a);     atomicAdd(&st[64+t],aq);
        atomicAdd(&st[128+t],b); atomicAdd(&st[192+t],bq2);
      }
    }
    gbar(p.cnt, bph);

    // ---------- S3: bn1/bn2 apply + MLP + bn3 stats ----------
    {
      float* sa = TR; float* sh = TR+512;
      float* Sb1 = TR+5760; float* Sb2 = TR+6272;
      const float* st = p.bnacc + l*384;
      const float* bngL = p.bng + l*192;
      const float* bnbL = p.bnb + l*192;
      const int c = t&63, rg = t>>6;
      float mu1 = st[c]*(1.f/NB);
      float va1 = st[64+c]*(1.f/NB) - mu1*mu1;
      float mu2 = st[128+c]*(1.f/NB);
      float va2 = st[192+c]*(1.f/NB) - mu2*mu2;
      float h1 = bngL[c]*(Sb1[rg*64+c]-mu1)*rsqrtf(va1+1e-5f)+bnbL[c];
      float h2 = bngL[64+c]*(Sb2[rg*64+c]-mu2)*rsqrtf(va2+1e-5f)+bnbL[64+c];
      sa[rg*64+c] = h1+h2;
      __syncthreads();
      {
        const float* W1 = p.W1 + l*8192;
        const int hj = t&127, rq = t>>7;
        float aA = p.b1[l*128+hj], aB = aA;
        #pragma unroll 4
        for (int k=0;k<64;++k){
          float w = W1[k*128+hj];
          aA += sa[(rq*2  )*64+k]*w;
          aB += sa[(rq*2+1)*64+k]*w;
        }
        sh[(rq*2  )*128+hj] = fmaxf(aA,0.f);
        sh[(rq*2+1)*128+hj] = fmaxf(aB,0.f);
      }
      __syncthreads();
      {
        const float* W2 = p.W2 + l*8192;
        float mo = p.b2[l*64+c];
        #pragma unroll 8
        for (int k=0;k<128;++k) mo += sh[rg*128+k]*W2[k*64+c];
        float sm = sa[rg*64+c] + mo;
        smlpL[rg*64+c] = sm;
        if (l == NLAY-1) p.smlpG[(size_t)(row0+rg)*64+c] = sm;
      }
      __syncthreads();
      if (t < 64){
        float* st2 = p.bnacc + l*384;
        float a=0.f,aq=0.f;
        #pragma unroll
        for (int rl=0;rl<8;++rl){ float v = smlpL[rl*64+t]; a+=v; aq+=v*v; }
        atomicAdd(&st2[256+t],a); atomicAdd(&st2[320+t],aq);
      }
    }
    gbar(p.cnt, bph);
  }

  // ================= S4: output GEMM (block = 16 rows x half-cols) =================
  {
    const int rt = blk>>1, chf = blk&1;
    const int rows0 = rt*16;
    float* hsT = TR;
    const float* st = p.bnacc + 4*384;
    const float* g4 = p.bng + 4*192 + 128;
    const float* b4 = p.bnb + 896;
    #pragma unroll
    for (int i=0;i<2;++i){
      int idx = t + 512*i;
      int k = idx&63, rr = idx>>6;
      float mu = st[256+k]*(1.f/NB);
      float va = st[320+k]*(1.f/NB) - mu*mu;
      hsT[k*20+rr] = g4[k]*(p.smlpG[(size_t)(rows0+rr)*64+k]-mu)*rsqrtf(va+1e-5f)+b4[k];
    }
    __syncthreads();
    const int cc = chf*2048 + t*4;
    float4 acc[16];
    {
      float4 bv = *(const float4*)&p.outb[cc];
      #pragma unroll
      for (int rr=0;rr<16;++rr) acc[rr]=bv;
    }
    #pragma unroll 4
    for (int k=0;k<64;++k){
      float4 w = *(const float4*)&p.outW[(size_t)k*4096+cc];
      const float4* hp = (const float4*)&hsT[k*20];
      float4 h0=hp[0], h1=hp[1], h2=hp[2], h3=hp[3];
      acc[0].x+=h0.x*w.x;  acc[0].y+=h0.x*w.y;  acc[0].z+=h0.x*w.z;  acc[0].w+=h0.x*w.w;
      acc[1].x+=h0.y*w.x;  acc[1].y+=h0.y*w.y;  acc[1].z+=h0.y*w.z;  acc[1].w+=h0.y*w.w;
      acc[2].x+=h0.z*w.x;  acc[2].y+=h0.z*w.y;  acc[2].z+=h0.z*w.z;  acc[2].w+=h0.z*w.w;
      acc[3].x+=h0.w*w.x;  acc[3].y+=h0.w*w.y;  acc[3].z+=h0.w*w.z;  acc[3].w+=h0.w*w.w;
      acc[4].x+=h1.x*w.x;  acc[4].y+=h1.x*w.y;  acc[4].z+=h1.x*w.z;  acc[4].w+=h1.x*w.w;
      acc[5].x+=h1.y*w.x;  acc[5].y+=h1.y*w.y;  acc[5].z+=h1.y*w.z;  acc[5].w+=h1.y*w.w;
      acc[6].x+=h1.z*w.x;  acc[6].y+=h1.z*w.y;  acc[6].z+=h1.z*w.z;  acc[6].w+=h1.z*w.w;
      acc[7].x+=h1.w*w.x;  acc[7].y+=h1.w*w.y;  acc[7].z+=h1.w*w.z;  acc[7].w+=h1.w*w.w;
      acc[8].x+=h2.x*w.x;  acc[8].y+=h2.x*w.y;  acc[8].z+=h2.x*w.z;  acc[8].w+=h2.x*w.w;
      acc[9].x+=h2.y*w.x;  acc[9].y+=h2.y*w.y;  acc[9].z+=h2.y*w.z;  acc[9].w+=h2.y*w.w;
      acc[10].x+=h2.z*w.x; acc[10].y+=h2.z*w.y; acc[10].z+=h2.z*w.z; acc[10].w+=h2.z*w.w;
      acc[11].x+=h2.w*w.x; acc[11].y+=h2.w*w.y; acc[11].z+=h2.w*w.z; acc[11].w+=h2.w*w.w;
      acc[12].x+=h3.x*w.x; acc[12].y+=h3.x*w.y; acc[12].z+=h3.x*w.z; acc[12].w+=h3.x*w.w;
      acc[13].x+=h3.y*w.x; acc[13].y+=h3.y*w.y; acc[13].z+=h3.y*w.z; acc[13].w+=h3.y*w.w;
      acc[14].x+=h3.z*w.x; acc[14].y+=h3.z*w.y; acc[14].z+=h3.z*w.z; acc[14].w+=h3.z*w.w;
      acc[15].x+=h3.w*w.x; acc[15].y+=h3.w*w.y; acc[15].z+=h3.w*w.z; acc[15].w+=h3.w*w.w;
    }
    #pragma unroll
    for (int rr=0;rr<16;++rr)
      *(float4*)&p.out[(size_t)(rows0+rr)*4096+cc] = acc[rr];
  }
}

extern "C" void kernel_launch(void* const* d_in, const int* in_sizes, int n_in,
                              void* d_out, int out_size, void* d_ws, size_t ws_size,
                              hipStream_t stream)
{
  (void)in_sizes; (void)n_in; (void)out_size; (void)ws_size;
  float* ws = (float*)d_ws;
  // layout: [0..64) cnt, [64..128) hsum, [128..2048) bnacc  -> all zeroed below
  unsigned* cnt = (unsigned*)ws;
  float* hsum  = ws + 64;
  float* bnacc = ws + 128;
  unsigned short* Kb = (unsigned short*)(ws + 2048);   // 4*2048*32 bf16 = 131072 fl
  unsigned short* Vt = Kb + 262144;                    // 4*16*2048 bf16 = 32768 fl
  float* h0p   = (float*)(Vt + 65536);                 // 2*2048*64 = 262144 fl
  float* smlpG = h0p + 262144;                         // 131072 fl

  hipMemsetAsync(d_ws, 0, 2048*sizeof(float), stream);

  MP p;
  p.x = (const float*)d_in[0];   p.tt = (const float*)d_in[1];
  p.freqs = (const float*)d_in[2];
  p.fc1W = (const float*)d_in[3]; p.fc1b = (const float*)d_in[4];
  p.fc2W = (const float*)d_in[5]; p.fc2b = (const float*)d_in[6];
  p.nodeW = (const float*)d_in[7]; p.nodeb = (const float*)d_in[8];
  p.tprojW = (const float*)d_in[9]; p.tprojb = (const float*)d_in[10];
  p.tcatW = (const float*)d_in[11]; p.tcatb = (const float*)d_in[12];
  p.penb = (const float*)d_in[14];
  p.pelW = (const float*)d_in[15]; p.pelb = (const float*)d_in[16];
  p.catW = (const float*)d_in[17]; p.catb = (const float*)d_in[18];
  p.convWg = (const float*)d_in[19];
  p.gruWih = (const float*)d_in[20]; p.grubih = (const float*)d_in[21];
  p.gruWhh = (const float*)d_in[22]; p.grubhh = (const float*)d_in[23];
  p.Wqkv = (const float*)d_in[24]; p.bqkv = (const float*)d_in[25];
  p.Wo = (const float*)d_in[26];  p.bo = (const float*)d_in[27];
  p.bng = (const float*)d_in[28]; p.bnb = (const float*)d_in[29];
  p.W1 = (const float*)d_in[30];  p.b1 = (const float*)d_in[31];
  p.W2 = (const float*)d_in[32];  p.b2 = (const float*)d_in[33];
  p.outW = (const float*)d_in[34]; p.outb = (const float*)d_in[35];
  p.out = (float*)d_out;
  p.cnt = cnt; p.hsum = hsum; p.bnacc = bnacc;
  p.Kb = Kb; p.Vt = Vt; p.h0p = h0p; p.smlpG = smlpG;

  k_mega<<<dim3(256), dim3(512), 0, stream>>>(p);
}

// Round 8
// 534.101 us; speedup vs baseline: 1.6338x; 1.6338x over previous
//
#include <hip/hip_runtime.h>

#define NB 2048
#define HDM 64
#define NLAY 5

typedef __bf16 bf16x8 __attribute__((ext_vector_type(8)));
typedef float v4f __attribute__((ext_vector_type(4)));

__device__ __forceinline__ float sigmoidf_(float x){ return 1.f/(1.f+__expf(-x)); }
__device__ __forceinline__ float tanhfast_(float x){
  x = fminf(fmaxf(x, -15.f), 15.f);
  float e = __expf(2.f*x);
  return (e-1.f)/(e+1.f);
}
__device__ __forceinline__ unsigned short f2b_rne(float f){
  unsigned u = __float_as_uint(f);
  unsigned r = u + 0x7FFFu + ((u>>16)&1u);
  return (unsigned short)(r>>16);
}
__device__ __forceinline__ unsigned pk2(float a, float b){
  unsigned ua = (__float_as_uint(a) + 0x8000u) >> 16;
  unsigned ub = (__float_as_uint(b) + 0x8000u) & 0xFFFF0000u;
  return ua | ub;
}

// ---------------- Kernel: time-embedding + GEMM1 (8-way K-split, 4x4 per thread) ----------
// grid 1024 x 256.  (identical to round-5 measured-good version)
__global__ __launch_bounds__(256) void k_pre(
    const float* __restrict__ x, const float* __restrict__ tt,
    const float* __restrict__ freqs,
    const float* __restrict__ fc1W, const float* __restrict__ fc1b,
    const float* __restrict__ fc2W, const float* __restrict__ fc2b,
    const float* __restrict__ tprojW, const float* __restrict__ tprojb,
    const float* __restrict__ nodeW,
    float* __restrict__ h0p, float* __restrict__ htime,
    float* __restrict__ zero_region)   // hsum(320) + bnacc(1920) contiguous
{
  __shared__ float xs[16*260];
  __shared__ float tb0[128];
  __shared__ float tb1[128];
  const int t = threadIdx.x, blk = blockIdx.x;
  const int r = t>>6, c = t&63;

  if (blk == 0){
    for (int i = t; i < 320 + 1920; i += 256) zero_region[i] = 0.f;
  }

  {
    const int row = blk*2 + (r&1);
    const float tv = tt[row];
    if (r < 2){
      float te[16];
      #pragma unroll
      for (int j=0;j<8;++j){
        float sv, cv;
        __sincosf(6.28318530717958647692f*tv*freqs[j], &sv, &cv);
        te[j]=sv; te[j+8]=cv;
      }
      float a = fc1b[c];
      #pragma unroll
      for (int j=0;j<16;++j) a += te[j]*fc1W[j*64+c];
      tb0[r*64+c] = a*sigmoidf_(a);
    }
    __syncthreads();
    if (r < 2){
      float b2 = fc2b[c];
      #pragma unroll 8
      for (int k=0;k<64;++k) b2 += tb0[r*64+k]*fc2W[k*64+c];
      tb1[r*64+c] = b2;
    }
    __syncthreads();
    if (r < 2){
      float hti = tprojb[c];
      #pragma unroll 8
      for (int k=0;k<64;++k) hti += tb1[r*64+k]*tprojW[k*64+c];
      htime[row*64+c] = hti;
    }
  }

  const int rg = blk>>3, kq = blk&7;
  const int rows0 = rg*16, k0 = kq*512;
  const int col4 = (t&15)*4, rq4 = ((t>>4)&3)*4, ksub = (t>>6)*64;

  float4 a0={0,0,0,0}, a1={0,0,0,0}, a2={0,0,0,0}, a3={0,0,0,0};

  for (int ch=0; ch<2; ++ch){
    __syncthreads();
    #pragma unroll
    for (int i=0;i<4;++i){
      int fi = t + 256*i;
      int xr = fi>>6, kk = (fi&63)<<2;
      *(float4*)&xs[xr*260+kk] = *(const float4*)&x[(size_t)(rows0+xr)*4096 + k0 + ch*256 + kk];
    }
    __syncthreads();
    const float* wp = &nodeW[(size_t)(k0 + ch*256 + ksub)*64 + col4];
    const float* xp = &xs[rq4*260 + ksub];
    #pragma unroll 8
    for (int kk=0; kk<64; ++kk){
      float4 w  = *(const float4*)&wp[kk*64];
      float x0 = xp[kk], x1 = xp[260+kk], x2 = xp[520+kk], x3 = xp[780+kk];
      a0.x += x0*w.x; a0.y += x0*w.y; a0.z += x0*w.z; a0.w += x0*w.w;
      a1.x += x1*w.x; a1.y += x1*w.y; a1.z += x1*w.z; a1.w += x1*w.w;
      a2.x += x2*w.x; a2.y += x2*w.y; a2.z += x2*w.z; a2.w += x2*w.w;
      a3.x += x3*w.x; a3.y += x3*w.y; a3.z += x3*w.z; a3.w += x3*w.w;
    }
  }
  __syncthreads();
  {
    const int kqi = t>>6;
    *(float4*)&xs[(kqi*16 + rq4 + 0)*64 + col4] = a0;
    *(float4*)&xs[(kqi*16 + rq4 + 1)*64 + col4] = a1;
    *(float4*)&xs[(kqi*16 + rq4 + 2)*64 + col4] = a2;
    *(float4*)&xs[(kqi*16 + rq4 + 3)*64 + col4] = a3;
  }
  __syncthreads();
  {
    const int row = t>>4, c4 = (t&15)*4;
    float4 s = {0,0,0,0};
    #pragma unroll
    for (int q=0;q<4;++q){
      float4 v = *(const float4*)&xs[(q*16+row)*64 + c4];
      s.x+=v.x; s.y+=v.y; s.z+=v.z; s.w+=v.w;
    }
    *(float4*)&h0p[(size_t)kq*(NB*HDM) + (rows0+row)*64 + c4] = s;
  }
}

// ---------------- Kernel A (per layer): [assemble | bn3 prev] + hsum(l0) + gh + QKV packs --
// grid 256 x 256: 8 rows/block.
__global__ __launch_bounds__(256) void k_A(
    const float* __restrict__ smlp,
    const float* __restrict__ bnaccPrev,
    const float* __restrict__ gPrev, const float* __restrict__ bPrev,
    float* __restrict__ hbuf, float* __restrict__ hsumL,
    const float* __restrict__ Whh, const float* __restrict__ bhh,
    const float* __restrict__ Wq,  const float* __restrict__ bq,
    float* __restrict__ gh,
    unsigned short* __restrict__ Qb, unsigned short* __restrict__ Kb,
    unsigned short* __restrict__ Vt,
    // assemble inputs (used only when first):
    const float* __restrict__ h0p, const float* __restrict__ htime,
    const float* __restrict__ nodeb,
    const float* __restrict__ tcatW, const float* __restrict__ tcatb,
    const float* __restrict__ penb, const float* __restrict__ pelW,
    const float* __restrict__ pelb,
    const float* __restrict__ catW, const float* __restrict__ catb,
    int first)
{
  __shared__ float sa[8*64];
  __shared__ float bufA[8*64];
  __shared__ float bufB[8*64];
  __shared__ float bufC[8*64];
  __shared__ float cvec[64];
  const int t = threadIdx.x, blk = blockIdx.x;
  const int row0 = blk*8;

  if (first){
    if (t < 64){
      float pl[16];
      #pragma unroll
      for (int j=0;j<16;++j){
        float a = pelb[j];
        for (int w=0;w<20;++w) a += penb[w]*pelW[w*16+j];
        pl[j]=a;
      }
      float a = catb[t];
      #pragma unroll
      for (int j=0;j<16;++j) a += pl[j]*catW[(64+j)*64+t];
      cvec[t]=a;
    }
    #pragma unroll
    for (int i=0;i<2;++i){
      int idx = t + 256*i;
      int rl = idx>>6, c = idx&63;
      int row = row0 + rl;
      float h0 = nodeb[c];
      #pragma unroll
      for (int q=0;q<8;++q) h0 += h0p[(size_t)q*(NB*HDM) + (size_t)row*64 + c];
      bufA[idx] = h0;
      bufB[idx] = htime[(size_t)row*64+c];
    }
    __syncthreads();
    #pragma unroll
    for (int i=0;i<2;++i){
      int idx = t + 256*i;
      int rl = idx>>6, c = idx&63;
      float a = tcatb[c];
      #pragma unroll 4
      for (int k=0;k<64;++k){
        a += bufA[rl*64+k]*tcatW[k*64+c];
        a += bufB[rl*64+k]*tcatW[(64+k)*64+c];
      }
      bufC[idx] = a;
    }
    __syncthreads();
    #pragma unroll
    for (int i=0;i<2;++i){
      int idx = t + 256*i;
      int rl = idx>>6, c = idx&63;
      float hv = cvec[c];
      #pragma unroll 8
      for (int k=0;k<64;++k) hv += bufC[rl*64+k]*catW[k*64+c];
      sa[idx] = hv;
      hbuf[(size_t)(row0+rl)*64+c] = hv;
    }
    __syncthreads();
    if (t < 64){   // hsum only needed for layer 0 (l>0 is analytic: NB*beta)
      float s = 0.f;
      #pragma unroll
      for (int rl=0;rl<8;++rl) s += sa[rl*64+t];
      atomicAdd(&hsumL[t], s);
    }
  } else {
    #pragma unroll
    for (int i=0;i<2;++i){
      int idx = t + 256*i;
      int rl = idx>>6, c = idx&63;
      int row = row0 + rl;
      float mu = bnaccPrev[256+c]*(1.f/NB);
      float va = bnaccPrev[320+c]*(1.f/NB) - mu*mu;
      float hv = gPrev[c]*(smlp[(size_t)row*64+c]-mu)*rsqrtf(va+1e-5f)+bPrev[c];
      hbuf[(size_t)row*64+c] = hv;
      sa[idx] = hv;
    }
    __syncthreads();
  }

  if (t < 192){
    const int cc = t;
    float ag[8], aq[8];
    float bh = bhh[cc], bq_ = bq[cc];
    #pragma unroll
    for (int rl=0;rl<8;++rl){ ag[rl]=bh; aq[rl]=bq_; }
    #pragma unroll 4
    for (int k=0;k<64;++k){
      float wh = Whh[k*192+cc];
      float wq = Wq [k*192+cc];
      #pragma unroll
      for (int rl=0;rl<8;++rl){
        float hk = sa[rl*64+k];
        ag[rl] += hk*wh;
        aq[rl] += hk*wq;
      }
    }
    #pragma unroll
    for (int rl=0;rl<8;++rl){
      int rw = row0 + rl;
      gh[(size_t)rw*192+cc] = ag[rl];
      float aqv = aq[rl];
      if (cc < 64){
        int hd = cc>>4, dh = cc&15;
        size_t base = ((size_t)(hd<<11) + rw)*32;
        Qb[base+dh] = f2b_rne(aqv*0.25f);
        Qb[base+16+dh] = 0;
      } else if (cc < 128){
        int c2 = cc-64, hd = c2>>4, dh = c2&15;
        size_t base = ((size_t)(hd<<11) + rw)*32;
        Kb[base+dh] = f2b_rne(aqv);
        Kb[base+16+dh] = 0;
      } else {
        int c2 = cc-128, hd = c2>>4, dh = c2&15;
        Vt[((size_t)(hd*16+dh))*2048 + rw] = f2b_rne(aqv);
      }
    }
  }
}

// ---------------- Kernel B (per layer): attention + o-proj + GRU + bn1/bn2 stats ----------
// grid 256 x 512: 8 rows/block (padded to 16 in MFMA); wave w = (head w>>1, key-half w&1).
__global__ __launch_bounds__(512) void k_B(
    const float* __restrict__ hbuf, const float* __restrict__ gh,
    const float* __restrict__ hsumL, const float* __restrict__ bP3,  // prev bn3 beta
    const unsigned short* __restrict__ Qb, const unsigned short* __restrict__ Kb,
    const unsigned short* __restrict__ Vt,
    const float* __restrict__ Wg,   const float* __restrict__ Wih,
    const float* __restrict__ bih,  const float* __restrict__ Wo,
    const float* __restrict__ bo,
    float* __restrict__ s1, float* __restrict__ s2, float* __restrict__ bnaccL,
    int first)
{
  __shared__ float smv[64];
  __shared__ float gi[192];
  __shared__ unsigned short Pl[8*640];
  __shared__ float Os[8*272];
  __shared__ float ms[128], ls[128];
  __shared__ float oL[512];
  __shared__ float Sb1[512], Sb2[512];
  const int t = threadIdx.x, blk = blockIdx.x;
  const int row0 = blk*8;

  if (t < 64){
    float a = 0.f;
    if (first){
      #pragma unroll 8
      for (int k=0;k<64;++k) a += hsumL[k]*Wg[k*64+t];
    } else {
      #pragma unroll 8
      for (int k=0;k<64;++k) a += (2048.f*bP3[k])*Wg[k*64+t];
    }
    smv[t]=a;
  }
  __syncthreads();
  if (t < 192){
    float a = bih[t];
    #pragma unroll 8
    for (int k=0;k<64;++k) a += smv[k]*Wih[k*192+t];
    gi[t]=a;
  }

  // --- attention ---
  {
    const int w = t>>6, lane = t&63;
    const int q15 = lane&15, quad = lane>>4;
    const int head = w>>1, e = w&1;
    const int key00 = e*1024;
    unsigned short* Plw = &Pl[w*640];

    bf16x8 qf;
    if (q15 < 8){
      qf = *(const bf16x8*)&Qb[(((size_t)(head<<11)) + (row0+q15))*32 + quad*8];
    } else {
      #pragma unroll
      for (int j=0;j<8;++j) qf[j] = (__bf16)0.0f;
    }
    const unsigned short* Kb_h = Kb + ((size_t)(head<<11))*32;
    const unsigned short* Vrow = Vt + ((size_t)(head*16+q15))*2048;

    v4f O = {0.f,0.f,0.f,0.f};
    float m = -1e30f, lsum = 0.f;

    bf16x8 kf0 = *(const bf16x8*)&Kb_h[(size_t)(key00 + q15)*32 + quad*8];
    bf16x8 kf1 = *(const bf16x8*)&Kb_h[(size_t)(key00 + 16 + q15)*32 + quad*8];
    bf16x8 vf  = *(const bf16x8*)&Vrow[key00 + quad*8];

    for (int c=0; c<32; ++c){
      bf16x8 nk0, nk1, nv;
      if (c < 31){
        int nk = key00 + (c+1)*32;
        nk0 = *(const bf16x8*)&Kb_h[(size_t)(nk + q15)*32 + quad*8];
        nk1 = *(const bf16x8*)&Kb_h[(size_t)(nk + 16 + q15)*32 + quad*8];
        nv  = *(const bf16x8*)&Vrow[nk + quad*8];
      }
      v4f z = {0.f,0.f,0.f,0.f};
      v4f sc0 = __builtin_amdgcn_mfma_f32_16x16x32_bf16(kf0, qf, z, 0,0,0);
      v4f sc1 = __builtin_amdgcn_mfma_f32_16x16x32_bf16(kf1, qf, z, 0,0,0);
      float cmax = fmaxf(fmaxf(fmaxf(sc0[0],sc0[1]),fmaxf(sc0[2],sc0[3])),
                         fmaxf(fmaxf(sc1[0],sc1[1]),fmaxf(sc1[2],sc1[3])));
      cmax = fmaxf(cmax, __shfl_xor(cmax,16,64));
      cmax = fmaxf(cmax, __shfl_xor(cmax,32,64));
      float mnew = fmaxf(m, cmax);
      float alpha = __expf(m - mnew);
      float p0=__expf(sc0[0]-mnew), p1=__expf(sc0[1]-mnew), p2=__expf(sc0[2]-mnew), p3=__expf(sc0[3]-mnew);
      float p4=__expf(sc1[0]-mnew), p5=__expf(sc1[1]-mnew), p6=__expf(sc1[2]-mnew), p7=__expf(sc1[3]-mnew);
      lsum = alpha*lsum + ((p0+p1)+(p2+p3)+((p4+p5)+(p6+p7)));
      m = mnew;
      O[0]*=alpha; O[1]*=alpha; O[2]*=alpha; O[3]*=alpha;
      *(uint2*)&Plw[q15*40 + quad*4]      = make_uint2(pk2(p0,p1), pk2(p2,p3));
      *(uint2*)&Plw[q15*40 + 16 + quad*4] = make_uint2(pk2(p4,p5), pk2(p6,p7));
      asm volatile("s_waitcnt lgkmcnt(0)" ::: "memory");
      bf16x8 pf = *(const bf16x8*)&Plw[q15*40 + quad*8];
      O = __builtin_amdgcn_mfma_f32_16x16x32_bf16(vf, pf, O, 0,0,0);
      kf0 = nk0; kf1 = nk1; vf = nv;
    }
    lsum += __shfl_xor(lsum,16,64);
    lsum += __shfl_xor(lsum,32,64);
    #pragma unroll
    for (int j=0;j<4;++j) Os[w*272 + q15*17 + quad*4 + j] = O[j];
    if (quad==0){ ms[w*16+q15]=m; ls[w*16+q15]=lsum; }
  }
  __syncthreads();
  // merge two key-halves per head -> oL[8][64]
  {
    const int q = t>>6, c = t&63;
    const int head = c>>4, dh = c&15;
    const int w0 = head*2, w1 = w0+1;
    float m0 = ms[w0*16+q], m1 = ms[w1*16+q];
    float mm = fmaxf(m0,m1);
    float a0 = __expf(m0-mm), a1 = __expf(m1-mm);
    float ll = a0*ls[w0*16+q] + a1*ls[w1*16+q];
    float oo = a0*Os[w0*272+q*17+dh] + a1*Os[w1*272+q*17+dh];
    oL[q*64+c] = oo / ll;
  }
  __syncthreads();
  // o-proj + GRU
  {
    const int c = t&63, rg = t>>6;
    const int row = row0 + rg;
    float o2 = bo[c];
    #pragma unroll 8
    for (int k=0;k<64;++k) o2 += oL[rg*64+k]*Wo[k*64+c];
    float hv = hbuf[(size_t)row*64+c];
    float s2v = o2 + hv;
    float ir  = gi[c]      + gh[(size_t)row*192+c];
    float iz  = gi[64+c]   + gh[(size_t)row*192+64+c];
    float inn = gi[128+c];
    float hn  = gh[(size_t)row*192+128+c];
    float rr_ = sigmoidf_(ir);
    float zz  = sigmoidf_(iz);
    float nn  = tanhfast_(inn + rr_*hn);
    float s1v = (1.f-zz)*nn + zz*hv + hv;   // hc + h
    s1[(size_t)row*64+c] = s1v;
    s2[(size_t)row*64+c] = s2v;
    Sb1[rg*64+c] = s1v;
    Sb2[rg*64+c] = s2v;
  }
  __syncthreads();
  if (t < 64){
    float a=0.f,aq=0.f,b=0.f,bq2=0.f;
    #pragma unroll
    for (int rl=0;rl<8;++rl){
      float v1 = Sb1[rl*64+t], v2 = Sb2[rl*64+t];
      a+=v1; aq+=v1*v1; b+=v2; bq2+=v2*v2;
    }
    atomicAdd(&bnaccL[t],a);     atomicAdd(&bnaccL[64+t],aq);
    atomicAdd(&bnaccL[128+t],b); atomicAdd(&bnaccL[192+t],bq2);
  }
}

// ---------------- Kernel C (per layer): bn1/bn2 apply + MLP + bn3 stats ----------------
// grid 256 x 256: 8 rows/block. (round-5 version)
__global__ __launch_bounds__(256) void k_C(
    const float* __restrict__ s1, const float* __restrict__ s2,
    const float* __restrict__ bngL, const float* __restrict__ bnbL,
    const float* __restrict__ W1, const float* __restrict__ b1,
    const float* __restrict__ W2, const float* __restrict__ b2,
    float* __restrict__ smlp, float* __restrict__ bnaccL)
{
  __shared__ float sa[8*64];
  __shared__ float sh[8*128];
  __shared__ float S2[8*64];
  const int t = threadIdx.x, blk = blockIdx.x;
  const int row0 = blk*8;

  #pragma unroll
  for (int i=0;i<2;++i){
    int idx = t + 256*i;
    int rl = idx>>6, c = idx&63;
    int row = row0 + rl;
    float mu1 = bnaccL[c]*(1.f/NB);
    float va1 = bnaccL[64+c]*(1.f/NB) - mu1*mu1;
    float mu2 = bnaccL[128+c]*(1.f/NB);
    float va2 = bnaccL[192+c]*(1.f/NB) - mu2*mu2;
    float h1 = bngL[c]*(s1[(size_t)row*64+c]-mu1)*rsqrtf(va1+1e-5f)+bnbL[c];
    float h2 = bngL[64+c]*(s2[(size_t)row*64+c]-mu2)*rsqrtf(va2+1e-5f)+bnbL[64+c];
    sa[idx] = h1+h2;
  }
  __syncthreads();
  {
    const int hj = t&127, rgq = t>>7;
    float a0v=b1[hj], a1v=b1[hj], a2v=b1[hj], a3v=b1[hj];
    #pragma unroll 4
    for (int k=0;k<64;++k){
      float w = W1[k*128+hj];
      a0v += sa[(rgq*4  )*64+k]*w;
      a1v += sa[(rgq*4+1)*64+k]*w;
      a2v += sa[(rgq*4+2)*64+k]*w;
      a3v += sa[(rgq*4+3)*64+k]*w;
    }
    sh[(rgq*4  )*128+hj] = fmaxf(a0v,0.f);
    sh[(rgq*4+1)*128+hj] = fmaxf(a1v,0.f);
    sh[(rgq*4+2)*128+hj] = fmaxf(a2v,0.f);
    sh[(rgq*4+3)*128+hj] = fmaxf(a3v,0.f);
  }
  __syncthreads();
  {
    const int c = t&63, rg = t>>6;
    float moa = b2[c], mob = b2[c];
    #pragma unroll 4
    for (int k=0;k<128;++k){
      float w = W2[k*64+c];
      moa += sh[(rg*2  )*128+k]*w;
      mob += sh[(rg*2+1)*128+k]*w;
    }
    #pragma unroll
    for (int i=0;i<2;++i){
      int rl = rg*2+i;
      float smv2 = sa[rl*64+c] + (i ? mob : moa);
      smlp[(size_t)(row0+rl)*64+c] = smv2;
      S2[rl*64+c] = smv2;
    }
  }
  __syncthreads();
  if (t<64){
    float a=0.f,aq=0.f;
    #pragma unroll
    for (int rl=0;rl<8;++rl){ float v=S2[rl*64+t]; a+=v; aq+=v*v; }
    atomicAdd(&bnaccL[256+t],a); atomicAdd(&bnaccL[320+t],aq);
  }
}

// ---------------- Kernel: GEMM2 with fused final bn3 (round-5 version) ----------------
__global__ __launch_bounds__(256) void k_out(
  const float* __restrict__ smlp, const float* __restrict__ bnacc4,
  const float* __restrict__ g4, const float* __restrict__ b4,
  const float* __restrict__ outW, const float* __restrict__ outb,
  float* __restrict__ out)
{
  __shared__ float hsT[64*20];
  const int t = threadIdx.x, blk = blockIdx.x;
  const int rg = blk>>2, cg = blk&3;
  const int rows0 = rg*16;
  #pragma unroll
  for (int i=0;i<4;++i){
    int idx = t + 256*i;
    int k = idx&63, rr = idx>>6;
    float mu = bnacc4[256+k]*(1.f/NB);
    float va = bnacc4[320+k]*(1.f/NB)-mu*mu;
    hsT[k*20+rr] = g4[k]*(smlp[(size_t)(rows0+rr)*64+k]-mu)*rsqrtf(va+1e-5f)+b4[k];
  }
  __syncthreads();
  const int cc = cg*1024 + t*4;
  float4 acc[16];
  {
    float4 bv = *(const float4*)&outb[cc];
    #pragma unroll
    for (int rr=0;rr<16;++rr) acc[rr]=bv;
  }
  #pragma unroll 4
  for (int k=0;k<64;++k){
    float4 w = *(const float4*)&outW[(size_t)k*4096+cc];
    const float4* hp = (const float4*)&hsT[k*20];
    float4 h0=hp[0], h1=hp[1], h2=hp[2], h3=hp[3];
    acc[0].x+=h0.x*w.x;  acc[0].y+=h0.x*w.y;  acc[0].z+=h0.x*w.z;  acc[0].w+=h0.x*w.w;
    acc[1].x+=h0.y*w.x;  acc[1].y+=h0.y*w.y;  acc[1].z+=h0.y*w.z;  acc[1].w+=h0.y*w.w;
    acc[2].x+=h0.z*w.x;  acc[2].y+=h0.z*w.y;  acc[2].z+=h0.z*w.z;  acc[2].w+=h0.z*w.w;
    acc[3].x+=h0.w*w.x;  acc[3].y+=h0.w*w.y;  acc[3].z+=h0.w*w.z;  acc[3].w+=h0.w*w.w;
    acc[4].x+=h1.x*w.x;  acc[4].y+=h1.x*w.y;  acc[4].z+=h1.x*w.z;  acc[4].w+=h1.x*w.w;
    acc[5].x+=h1.y*w.x;  acc[5].y+=h1.y*w.y;  acc[5].z+=h1.y*w.z;  acc[5].w+=h1.y*w.w;
    acc[6].x+=h1.z*w.x;  acc[6].y+=h1.z*w.y;  acc[6].z+=h1.z*w.z;  acc[6].w+=h1.z*w.w;
    acc[7].x+=h1.w*w.x;  acc[7].y+=h1.w*w.y;  acc[7].z+=h1.w*w.z;  acc[7].w+=h1.w*w.w;
    acc[8].x+=h2.x*w.x;  acc[8].y+=h2.x*w.y;  acc[8].z+=h2.x*w.z;  acc[8].w+=h2.x*w.w;
    acc[9].x+=h2.y*w.x;  acc[9].y+=h2.y*w.y;  acc[9].z+=h2.y*w.z;  acc[9].w+=h2.y*w.w;
    acc[10].x+=h2.z*w.x; acc[10].y+=h2.z*w.y; acc[10].z+=h2.z*w.z; acc[10].w+=h2.z*w.w;
    acc[11].x+=h2.w*w.x; acc[11].y+=h2.w*w.y; acc[11].z+=h2.w*w.z; acc[11].w+=h2.w*w.w;
    acc[12].x+=h3.x*w.x; acc[12].y+=h3.x*w.y; acc[12].z+=h3.x*w.z; acc[12].w+=h3.x*w.w;
    acc[13].x+=h3.y*w.x; acc[13].y+=h3.y*w.y; acc[13].z+=h3.y*w.z; acc[13].w+=h3.y*w.w;
    acc[14].x+=h3.z*w.x; acc[14].y+=h3.z*w.y; acc[14].z+=h3.z*w.z; acc[14].w+=h3.z*w.w;
    acc[15].x+=h3.w*w.x; acc[15].y+=h3.w*w.y; acc[15].z+=h3.w*w.z; acc[15].w+=h3.w*w.w;
  }
  #pragma unroll
  for (int rr=0;rr<16;++rr)
    *(float4*)&out[(size_t)(rows0+rr)*4096+cc] = acc[rr];
}

extern "C" void kernel_launch(void* const* d_in, const int* in_sizes, int n_in,
                              void* d_out, int out_size, void* d_ws, size_t ws_size,
                              hipStream_t stream)
{
  (void)in_sizes; (void)n_in; (void)out_size; (void)ws_size;
  const float* x      = (const float*)d_in[0];
  const float* tt     = (const float*)d_in[1];
  const float* freqs  = (const float*)d_in[2];
  const float* fc1W   = (const float*)d_in[3];
  const float* fc1b   = (const float*)d_in[4];
  const float* fc2W   = (const float*)d_in[5];
  const float* fc2b   = (const float*)d_in[6];
  const float* nodeW  = (const float*)d_in[7];
  const float* nodeb  = (const float*)d_in[8];
  const float* tprojW = (const float*)d_in[9];
  const float* tprojb = (const float*)d_in[10];
  const float* tcatW  = (const float*)d_in[11];
  const float* tcatb  = (const float*)d_in[12];
  const float* penb   = (const float*)d_in[14];
  const float* pelW   = (const float*)d_in[15];
  const float* pelb   = (const float*)d_in[16];
  const float* catW   = (const float*)d_in[17];
  const float* catb   = (const float*)d_in[18];
  const float* convWg = (const float*)d_in[19];
  const float* gruWih = (const float*)d_in[20];
  const float* grubih = (const float*)d_in[21];
  const float* gruWhh = (const float*)d_in[22];
  const float* grubhh = (const float*)d_in[23];
  const float* Wqkv   = (const float*)d_in[24];
  const float* bqkv   = (const float*)d_in[25];
  const float* Wo     = (const float*)d_in[26];
  const float* bo     = (const float*)d_in[27];
  const float* bng    = (const float*)d_in[28];
  const float* bnb    = (const float*)d_in[29];
  const float* W1     = (const float*)d_in[30];
  const float* b1     = (const float*)d_in[31];
  const float* W2     = (const float*)d_in[32];
  const float* b2     = (const float*)d_in[33];
  const float* outW   = (const float*)d_in[34];
  const float* outb   = (const float*)d_in[35];

  float* ws = (float*)d_ws;
  float* htime = ws;                  // 131072
  float* hbuf  = htime + 131072;      // 131072
  float* gh    = hbuf + 131072;       // 393216
  float* s1    = gh + 393216;         // 131072
  float* s2    = s1 + 131072;         // 131072
  float* smlp  = s2 + 131072;         // 131072
  float* hsum  = smlp + 131072;       // 320 (contiguous with bnacc for zeroing)
  float* bnacc = hsum + 320;          // 1920
  unsigned short* Qb = (unsigned short*)(bnacc + 1920);   // 262144 sh
  unsigned short* Kb = Qb + 262144;                       // 262144 sh
  unsigned short* Vt = Kb + 262144;                       // 65536 sh
  float* h0p  = (float*)(Vt + 65536); // 8*2048*64 = 1048576

  dim3 Blk(256);

  k_pre<<<dim3(1024), Blk, 0, stream>>>(x, tt, freqs, fc1W, fc1b, fc2W, fc2b,
                                        tprojW, tprojb, nodeW, h0p, htime, hsum);

  for (int l=0; l<NLAY; ++l){
    const float* bnaccPrev = (l==0) ? bnacc : bnacc + (l-1)*384;
    const float* gPrev = (l==0) ? bng : bng + (l-1)*192 + 128;
    const float* bPrev = (l==0) ? bnb : bnb + (l-1)*192 + 128;
    k_A<<<dim3(256), Blk, 0, stream>>>(smlp, bnaccPrev, gPrev, bPrev,
                                       hbuf, hsum,
                                       gruWhh + l*12288, grubhh + l*192,
                                       Wqkv + l*12288, bqkv + l*192,
                                       gh, Qb, Kb, Vt,
                                       h0p, htime, nodeb, tcatW, tcatb,
                                       penb, pelW, pelb, catW, catb,
                                       (l==0) ? 1 : 0);
    k_B<<<dim3(256), dim3(512), 0, stream>>>(hbuf, gh, hsum, bPrev,
                                       Qb, Kb, Vt,
                                       convWg + l*4096, gruWih + l*12288, grubih + l*192,
                                       Wo + l*4096, bo + l*64,
                                       s1, s2, bnacc + l*384, (l==0) ? 1 : 0);
    k_C<<<dim3(256), Blk, 0, stream>>>(s1, s2, bng + l*192, bnb + l*192,
                                       W1 + l*8192, b1 + l*128, W2 + l*8192, b2 + l*64,
                                       smlp, bnacc + l*384);
  }

  k_out<<<dim3(512), Blk, 0, stream>>>(smlp, bnacc + 4*384, bng + 896, bnb + 896,
                                       outW, outb, (float*)d_out);
}